// Round 3
// baseline (400.151 us; speedup 1.0000x reference)
//
#include <hip/hip_runtime.h>
#include <hip/hip_bf16.h>

// Fused causal MHA for MI355X (gfx950).
// Pipeline: cast f32->bf16, fused QKV GEMM (MFMA), flash attention, out GEMM.
// Workspace layout (48 MB total):
//   [0,8M)    x_bf16      (4096 x 1024)
//   [8,10M)   Wq_bf16     (1024 x 1024)
//   [10,12M)  Wk_bf16
//   [12,14M)  Wv_bf16
//   [14,16M)  Wo_bf16
//   [16,24M)  Q  (b,h,n,d) bf16, pre-scaled by 1/8
//   [24,32M)  K  (b,h,n,d) bf16
//   [32,40M)  V^T (b,h,d,n) bf16
//   [40,48M)  attn_out (b,n,h*dv) bf16

using bf16x8  = __attribute__((ext_vector_type(8))) __bf16;
using f32x4   = __attribute__((ext_vector_type(4))) float;
using ushort4v = __attribute__((ext_vector_type(4))) unsigned short;

__device__ __forceinline__ unsigned short f2bf(float f) {
    unsigned int u = __float_as_uint(f);
    u += 0x7FFFu + ((u >> 16) & 1u);   // round-to-nearest-even
    return (unsigned short)(u >> 16);
}

__global__ __launch_bounds__(256) void cast_bf16_kernel(
    const float* __restrict__ in, unsigned short* __restrict__ out, int n4) {
    int i = blockIdx.x * 256 + threadIdx.x;
    if (i >= n4) return;
    float4 f = reinterpret_cast<const float4*>(in)[i];
    ushort4v o;
    o.x = f2bf(f.x); o.y = f2bf(f.y); o.z = f2bf(f.z); o.w = f2bf(f.w);
    reinterpret_cast<ushort4v*>(out)[i] = o;
}

// casts 4 weight matrices (1024x1024 each) in one launch; blockIdx.y selects.
__global__ __launch_bounds__(256) void cast_w4_kernel(
    const float* __restrict__ w0, const float* __restrict__ w1,
    const float* __restrict__ w2, const float* __restrict__ w3,
    unsigned short* __restrict__ o0, unsigned short* __restrict__ o1,
    unsigned short* __restrict__ o2, unsigned short* __restrict__ o3) {
    const int z = blockIdx.y;
    const float* in = (z == 0) ? w0 : (z == 1) ? w1 : (z == 2) ? w2 : w3;
    unsigned short* out = (z == 0) ? o0 : (z == 1) ? o1 : (z == 2) ? o2 : o3;
    int i = blockIdx.x * 256 + threadIdx.x;   // 1024*1024/4 elements of float4
    float4 f = reinterpret_cast<const float4*>(in)[i];
    ushort4v o;
    o.x = f2bf(f.x); o.y = f2bf(f.y); o.z = f2bf(f.z); o.w = f2bf(f.w);
    reinterpret_cast<ushort4v*>(out)[i] = o;
}

// ---- 128x128 tile GEMM core: C = A(MxK) * B(NxK)^T, bf16 in, f32 acc ----
// 256 threads = 4 waves in 2x2; per wave 64x64 = 4x4 fragments of 16x16.
// LDS rows padded to 40 ushorts (80B) -> bank stride 20 mod 32, conflict-free.
__device__ __forceinline__ void gemm_core_128(
    const unsigned short* __restrict__ A, const unsigned short* __restrict__ B,
    int m0, int n0, int K,
    unsigned short* As, unsigned short* Bs, f32x4 acc[4][4]) {
    const int tid = threadIdx.x;
    const int lane = tid & 63;
    const int wid = tid >> 6;
    const int wr = wid >> 1, wc = wid & 1;
    const int l16 = lane & 15, lg = lane >> 4;

#pragma unroll
    for (int i = 0; i < 4; i++)
#pragma unroll
        for (int j = 0; j < 4; j++) acc[i][j] = f32x4{0.f, 0.f, 0.f, 0.f};

    for (int k0 = 0; k0 < K; k0 += 32) {
        __syncthreads();   // previous-iter LDS reads done before overwrite
#pragma unroll
        for (int it = 0; it < 2; ++it) {
            int chunk = it * 256 + tid;
            int row = chunk >> 2;
            int kc = (chunk & 3) * 8;
            *reinterpret_cast<bf16x8*>(&As[row * 40 + kc]) =
                *reinterpret_cast<const bf16x8*>(&A[(m0 + row) * K + k0 + kc]);
            *reinterpret_cast<bf16x8*>(&Bs[row * 40 + kc]) =
                *reinterpret_cast<const bf16x8*>(&B[(n0 + row) * K + k0 + kc]);
        }
        __syncthreads();
        bf16x8 af[4], bfr[4];
#pragma unroll
        for (int i = 0; i < 4; i++)
            af[i] = *reinterpret_cast<const bf16x8*>(&As[(64 * wr + 16 * i + l16) * 40 + 8 * lg]);
#pragma unroll
        for (int j = 0; j < 4; j++)
            bfr[j] = *reinterpret_cast<const bf16x8*>(&Bs[(64 * wc + 16 * j + l16) * 40 + 8 * lg]);
#pragma unroll
        for (int i = 0; i < 4; i++)
#pragma unroll
            for (int j = 0; j < 4; j++)
                acc[i][j] = __builtin_amdgcn_mfma_f32_16x16x32_bf16(af[i], bfr[j], acc[i][j], 0, 0, 0);
    }
}

// ---- QKV projection: z=0 -> Q (scaled 1/8), z=1 -> K, z=2 -> V^T ----
__global__ __launch_bounds__(256) void gemm_qkv_kernel(
    const unsigned short* __restrict__ xbf,
    const unsigned short* __restrict__ wq, const unsigned short* __restrict__ wk,
    const unsigned short* __restrict__ wv,
    const float* __restrict__ bq, const float* __restrict__ bk, const float* __restrict__ bv,
    unsigned short* __restrict__ q_ws, unsigned short* __restrict__ k_ws,
    unsigned short* __restrict__ vt_ws) {
    __shared__ __align__(16) unsigned short As[128 * 40];
    __shared__ __align__(16) unsigned short Bs[128 * 40];
    const int z = blockIdx.z;
    const unsigned short* W = (z == 0) ? wq : ((z == 1) ? wk : wv);
    const float* bias = (z == 0) ? bq : ((z == 1) ? bk : bv);
    const float scale = (z == 0) ? 0.125f : 1.0f;
    const int m0 = blockIdx.y * 128;
    const int n0 = blockIdx.x * 128;

    f32x4 acc[4][4];
    gemm_core_128(xbf, W, m0, n0, 1024, As, Bs, acc);

    const int tid = threadIdx.x;
    const int lane = tid & 63;
    const int wid = tid >> 6;
    const int wr = wid >> 1, wc = wid & 1;
    const int l16 = lane & 15, lg = lane >> 4;

#pragma unroll
    for (int j = 0; j < 4; j++) {
        const int c = n0 + 64 * wc + 16 * j + l16;   // output feature
        const float bc = bias[c];
        const int h = c >> 6, d = c & 63;
#pragma unroll
        for (int i = 0; i < 4; i++) {
            const int mb = m0 + 64 * wr + 16 * i + 4 * lg;   // + r
            if (z < 2) {
                unsigned short* dst = (z == 0) ? q_ws : k_ws;
#pragma unroll
                for (int r = 0; r < 4; r++) {
                    int m = mb + r;
                    int b = m >> 11, n = m & 2047;
                    float v = (acc[i][j][r] + bc) * scale;
                    dst[(((b * 16 + h) * 2048 + n) << 6) + d] = f2bf(v);
                }
            } else {
                int b = mb >> 11, n = mb & 2047;   // 4 consecutive n, same b
                ushort4v pk;
                pk.x = f2bf(acc[i][j][0] + bc);
                pk.y = f2bf(acc[i][j][1] + bc);
                pk.z = f2bf(acc[i][j][2] + bc);
                pk.w = f2bf(acc[i][j][3] + bc);
                *reinterpret_cast<ushort4v*>(&vt_ws[((b * 16 + h) * 64 + d) * 2048 + n]) = pk;
            }
        }
    }
}

// ---- Flash attention, causal. 1 wave = 16 q-rows; KV tiles of 32. ----
__global__ __launch_bounds__(256) void attn_kernel(
    const unsigned short* __restrict__ q_ws, const unsigned short* __restrict__ k_ws,
    const unsigned short* __restrict__ vt_ws, unsigned short* __restrict__ attn_out) {
    __shared__ __align__(16) unsigned short P_lds[4][16][40];   // per-wave, padded
    const int tid = threadIdx.x;
    const int wid = tid >> 6, lane = tid & 63;
    const int l16 = lane & 15, lg = lane >> 4;
    const int gwid = blockIdx.x * 4 + wid;
    const int bh = gwid >> 7;           // 0..31 = b*16+h
    const int q0 = (gwid & 127) << 4;   // q-tile start
    const unsigned short* qb = q_ws + bh * (2048 * 64);
    const unsigned short* kb = k_ws + bh * (2048 * 64);
    const unsigned short* vb = vt_ws + bh * (64 * 2048);

    // Q fragments (hoisted; Q pre-scaled by 1/8)
    bf16x8 aq0 = *reinterpret_cast<const bf16x8*>(&qb[(q0 + l16) * 64 + 8 * lg]);
    bf16x8 aq1 = *reinterpret_cast<const bf16x8*>(&qb[(q0 + l16) * 64 + 32 + 8 * lg]);

    f32x4 o[4];
#pragma unroll
    for (int j = 0; j < 4; j++) o[j] = f32x4{0.f, 0.f, 0.f, 0.f};
    float m_r[4] = {-1e30f, -1e30f, -1e30f, -1e30f};
    float l_r[4] = {0.f, 0.f, 0.f, 0.f};

    for (int kv0 = 0; kv0 < q0 + 16; kv0 += 32) {
        // S = Q K^T  (C-layout: row = q0+4*lg+r, col = kv0 + 16t + l16)
        f32x4 s0 = f32x4{0.f, 0.f, 0.f, 0.f}, s1 = f32x4{0.f, 0.f, 0.f, 0.f};
        {
            const unsigned short* kr0 = &kb[(kv0 + l16) * 64 + 8 * lg];
            bf16x8 k00 = *reinterpret_cast<const bf16x8*>(kr0);
            bf16x8 k01 = *reinterpret_cast<const bf16x8*>(kr0 + 32);
            s0 = __builtin_amdgcn_mfma_f32_16x16x32_bf16(aq0, k00, s0, 0, 0, 0);
            s0 = __builtin_amdgcn_mfma_f32_16x16x32_bf16(aq1, k01, s0, 0, 0, 0);
            const unsigned short* kr1 = &kb[(kv0 + 16 + l16) * 64 + 8 * lg];
            bf16x8 k10 = *reinterpret_cast<const bf16x8*>(kr1);
            bf16x8 k11 = *reinterpret_cast<const bf16x8*>(kr1 + 32);
            s1 = __builtin_amdgcn_mfma_f32_16x16x32_bf16(aq0, k10, s1, 0, 0, 0);
            s1 = __builtin_amdgcn_mfma_f32_16x16x32_bf16(aq1, k11, s1, 0, 0, 0);
        }
        // causal mask (exact per element; harmless on interior tiles)
#pragma unroll
        for (int r = 0; r < 4; r++) {
            int row = q0 + 4 * lg + r;
            if (kv0 + l16 > row) s0[r] = -1e30f;
            if (kv0 + 16 + l16 > row) s1[r] = -1e30f;
        }
        // online softmax: row reduce across the 16-lane column group
        float mx[4];
#pragma unroll
        for (int r = 0; r < 4; r++) {
            float v = fmaxf(s0[r], s1[r]);
            v = fmaxf(v, __shfl_xor(v, 1));
            v = fmaxf(v, __shfl_xor(v, 2));
            v = fmaxf(v, __shfl_xor(v, 4));
            v = fmaxf(v, __shfl_xor(v, 8));
            mx[r] = fmaxf(m_r[r], v);
        }
        float p0[4], p1[4], sf[4];
#pragma unroll
        for (int r = 0; r < 4; r++) {
            sf[r] = __expf(m_r[r] - mx[r]);
            m_r[r] = mx[r];
            p0[r] = __expf(s0[r] - mx[r]);
            p1[r] = __expf(s1[r] - mx[r]);
            float t = p0[r] + p1[r];
            t += __shfl_xor(t, 1);
            t += __shfl_xor(t, 2);
            t += __shfl_xor(t, 4);
            t += __shfl_xor(t, 8);
            l_r[r] = l_r[r] * sf[r] + t;
        }
#pragma unroll
        for (int j = 0; j < 4; j++) {
            o[j][0] *= sf[0]; o[j][1] *= sf[1]; o[j][2] *= sf[2]; o[j][3] *= sf[3];
        }
        // P (C-layout) -> bf16 A-fragment via per-wave LDS transpose
#pragma unroll
        for (int r = 0; r < 4; r++) {
            P_lds[wid][4 * lg + r][l16] = f2bf(p0[r]);
            P_lds[wid][4 * lg + r][16 + l16] = f2bf(p1[r]);
        }
        bf16x8 pf = *reinterpret_cast<const bf16x8*>(&P_lds[wid][l16][8 * lg]);
        // O += P * V   (B-frag from V^T: contiguous along kv)
#pragma unroll
        for (int j = 0; j < 4; j++) {
            bf16x8 bv = *reinterpret_cast<const bf16x8*>(&vb[(16 * j + l16) * 2048 + kv0 + 8 * lg]);
            o[j] = __builtin_amdgcn_mfma_f32_16x16x32_bf16(pf, bv, o[j], 0, 0, 0);
        }
    }
    // epilogue: normalize and store attn_out[b][n][h*64+c] bf16
    const int b = bh >> 4, h = bh & 15;
    float inv[4];
#pragma unroll
    for (int r = 0; r < 4; r++) inv[r] = 1.0f / l_r[r];
#pragma unroll
    for (int j = 0; j < 4; j++) {
#pragma unroll
        for (int r = 0; r < 4; r++) {
            int n = q0 + 4 * lg + r;
            attn_out[(size_t)(b * 2048 + n) * 1024 + h * 64 + 16 * j + l16] =
                f2bf(o[j][r] * inv[r]);
        }
    }
}

// ---- output projection: out = attn_out @ Wo^T (f32 out, no bias) ----
__global__ __launch_bounds__(256) void gemm_out_kernel(
    const unsigned short* __restrict__ abf, const unsigned short* __restrict__ wo,
    float* __restrict__ out) {
    __shared__ __align__(16) unsigned short As[128 * 40];
    __shared__ __align__(16) unsigned short Bs[128 * 40];
    const int m0 = blockIdx.y * 128;
    const int n0 = blockIdx.x * 128;
    f32x4 acc[4][4];
    gemm_core_128(abf, wo, m0, n0, 1024, As, Bs, acc);

    const int tid = threadIdx.x;
    const int lane = tid & 63;
    const int wid = tid >> 6;
    const int wr = wid >> 1, wc = wid & 1;
    const int l16 = lane & 15, lg = lane >> 4;
#pragma unroll
    for (int j = 0; j < 4; j++) {
        const int c = n0 + 64 * wc + 16 * j + l16;
#pragma unroll
        for (int i = 0; i < 4; i++) {
#pragma unroll
            for (int r = 0; r < 4; r++) {
                int m = m0 + 64 * wr + 16 * i + 4 * lg + r;
                out[(size_t)m * 1024 + c] = acc[i][j][r];
            }
        }
    }
}

extern "C" void kernel_launch(void* const* d_in, const int* in_sizes, int n_in,
                              void* d_out, int out_size, void* d_ws, size_t ws_size,
                              hipStream_t stream) {
    const float* x  = (const float*)d_in[0];
    const float* Wq = (const float*)d_in[1];
    const float* bq = (const float*)d_in[2];
    const float* Wk = (const float*)d_in[3];
    const float* bk = (const float*)d_in[4];
    const float* Wv = (const float*)d_in[5];
    const float* bv = (const float*)d_in[6];
    const float* Wo = (const float*)d_in[7];
    float* out = (float*)d_out;

    char* ws = (char*)d_ws;
    unsigned short* xbf  = (unsigned short*)(ws);
    unsigned short* wqbf = (unsigned short*)(ws + (8u  << 20));
    unsigned short* wkbf = (unsigned short*)(ws + (10u << 20));
    unsigned short* wvbf = (unsigned short*)(ws + (12u << 20));
    unsigned short* wobf = (unsigned short*)(ws + (14u << 20));
    unsigned short* qws  = (unsigned short*)(ws + (16u << 20));
    unsigned short* kws  = (unsigned short*)(ws + (24u << 20));
    unsigned short* vtws = (unsigned short*)(ws + (32u << 20));
    unsigned short* aows = (unsigned short*)(ws + (40u << 20));

    // casts: x (4096x1024) + 4 weights (1024x1024 each, one fused launch)
    cast_bf16_kernel<<<4096, 256, 0, stream>>>(x, xbf, 4096 * 1024 / 4);
    cast_w4_kernel<<<dim3(1024, 4), 256, 0, stream>>>(
        Wq, Wk, Wv, Wo, wqbf, wkbf, wvbf, wobf);

    // QKV projections (z = 0/1/2 -> Q/K/V)
    gemm_qkv_kernel<<<dim3(8, 32, 3), 256, 0, stream>>>(
        xbf, wqbf, wkbf, wvbf, bq, bk, bv, qws, kws, vtws);

    // flash attention: 4096 waves (16 q-rows each), 4 per block
    attn_kernel<<<1024, 256, 0, stream>>>(qws, kws, vtws, aows);

    // output projection
    gemm_out_kernel<<<dim3(8, 32, 1), 256, 0, stream>>>(aows, wobf, out);
}

// Round 4
// 281.068 us; speedup vs baseline: 1.4237x; 1.4237x over previous
//
#include <hip/hip_runtime.h>
#include <hip/hip_bf16.h>

// Fused causal MHA for MI355X (gfx950).
// Round-3 changes vs baseline:
//  * GEMMs: global_load_lds width-16 staging, linear LDS (m97 structure).
//  * Attention: swapped QK^T (lane owns one q-row -> 2-shfl softmax),
//    paired q-tiles (t, 127-t) per wave (kills causal tail, shares K/V loads),
//    K register prefetch.
// Workspace layout (48 MB):
//   [0,8M) x_bf16 | [8,16M) Wq/Wk/Wv/Wo bf16 (2M each)
//   [16,24M) Q (b,h,n,d) bf16 pre-scaled 1/8 | [24,32M) K (b,h,n,d)
//   [32,40M) V^T (b,h,d,n) | [40,48M) attn_out (b,n,h*dv) bf16

using bf16x8   = __attribute__((ext_vector_type(8))) __bf16;
using f32x4    = __attribute__((ext_vector_type(4))) float;
using ushort4v = __attribute__((ext_vector_type(4))) unsigned short;

__device__ __forceinline__ unsigned short f2bf(float f) {
    unsigned int u = __float_as_uint(f);
    u += 0x7FFFu + ((u >> 16) & 1u);   // round-to-nearest-even
    return (unsigned short)(u >> 16);
}

__device__ __forceinline__ void gll16(const void* g, void* l) {
    __builtin_amdgcn_global_load_lds(
        (const __attribute__((address_space(1))) void*)g,
        (__attribute__((address_space(3))) void*)l, 16, 0, 0);
}

__global__ __launch_bounds__(256) void cast_bf16_kernel(
    const float* __restrict__ in, unsigned short* __restrict__ out, int n4) {
    int i = blockIdx.x * 256 + threadIdx.x;
    if (i >= n4) return;
    float4 f = reinterpret_cast<const float4*>(in)[i];
    ushort4v o;
    o.x = f2bf(f.x); o.y = f2bf(f.y); o.z = f2bf(f.z); o.w = f2bf(f.w);
    reinterpret_cast<ushort4v*>(out)[i] = o;
}

__global__ __launch_bounds__(256) void cast_w4_kernel(
    const float* __restrict__ w0, const float* __restrict__ w1,
    const float* __restrict__ w2, const float* __restrict__ w3,
    unsigned short* __restrict__ o0, unsigned short* __restrict__ o1,
    unsigned short* __restrict__ o2, unsigned short* __restrict__ o3) {
    const int z = blockIdx.y;
    const float* in = (z == 0) ? w0 : (z == 1) ? w1 : (z == 2) ? w2 : w3;
    unsigned short* out = (z == 0) ? o0 : (z == 1) ? o1 : (z == 2) ? o2 : o3;
    int i = blockIdx.x * 256 + threadIdx.x;
    float4 f = reinterpret_cast<const float4*>(in)[i];
    ushort4v o;
    o.x = f2bf(f.x); o.y = f2bf(f.y); o.z = f2bf(f.z); o.w = f2bf(f.w);
    reinterpret_cast<ushort4v*>(out)[i] = o;
}

// ---- 128x128 GEMM core, global_load_lds staging (m97 structure) ----
// C = A(MxK) * B(NxK)^T. LDS linear [128][32] bf16 per operand (8 KB each).
// 4 waves 2x2; per wave 64x64 out = 4x4 16x16x32 MFMA frags.
__device__ __forceinline__ void gemm_core_128(
    const unsigned short* __restrict__ A, const unsigned short* __restrict__ B,
    int m0, int n0, int K,
    unsigned short* As, unsigned short* Bs, f32x4 acc[4][4]) {
    const int tid = threadIdx.x;
    const int lane = tid & 63;
    const int wid = tid >> 6;
    const int wr = wid >> 1, wc = wid & 1;
    const int l16 = lane & 15, lg = lane >> 4;

#pragma unroll
    for (int i = 0; i < 4; i++)
#pragma unroll
        for (int j = 0; j < 4; j++) acc[i][j] = f32x4{0.f, 0.f, 0.f, 0.f};

    // staging: wave w, chunk c covers rows c*64 + w*16 + lane/4, elem col (lane&3)*8
    const int srow = lane >> 2;
    const int scol = (lane & 3) * 8;
    const unsigned short* Ab0 = &A[(size_t)(m0 + wid * 16 + srow) * K + scol];
    const unsigned short* Ab1 = &A[(size_t)(m0 + 64 + wid * 16 + srow) * K + scol];
    const unsigned short* Bb0 = &B[(size_t)(n0 + wid * 16 + srow) * K + scol];
    const unsigned short* Bb1 = &B[(size_t)(n0 + 64 + wid * 16 + srow) * K + scol];
    unsigned short* AsW0 = As + (wid * 16) * 32;        // wave-uniform LDS bases
    unsigned short* AsW1 = As + (64 + wid * 16) * 32;
    unsigned short* BsW0 = Bs + (wid * 16) * 32;
    unsigned short* BsW1 = Bs + (64 + wid * 16) * 32;

    for (int k0 = 0; k0 < K; k0 += 32) {
        __syncthreads();                   // prev-iter LDS reads done
        gll16(Ab0 + k0, AsW0);
        gll16(Ab1 + k0, AsW1);
        gll16(Bb0 + k0, BsW0);
        gll16(Bb1 + k0, BsW1);
        __syncthreads();                   // compiler drains vmcnt before barrier
        bf16x8 af[4], bfr[4];
#pragma unroll
        for (int i = 0; i < 4; i++)
            af[i] = *reinterpret_cast<const bf16x8*>(&As[(64 * wr + 16 * i + l16) * 32 + 8 * lg]);
#pragma unroll
        for (int j = 0; j < 4; j++)
            bfr[j] = *reinterpret_cast<const bf16x8*>(&Bs[(64 * wc + 16 * j + l16) * 32 + 8 * lg]);
#pragma unroll
        for (int i = 0; i < 4; i++)
#pragma unroll
            for (int j = 0; j < 4; j++)
                acc[i][j] = __builtin_amdgcn_mfma_f32_16x16x32_bf16(af[i], bfr[j], acc[i][j], 0, 0, 0);
    }
}

// ---- QKV projection: z=0 -> Q (scaled 1/8), z=1 -> K, z=2 -> V^T ----
__global__ __launch_bounds__(256) void gemm_qkv_kernel(
    const unsigned short* __restrict__ xbf,
    const unsigned short* __restrict__ wq, const unsigned short* __restrict__ wk,
    const unsigned short* __restrict__ wv,
    const float* __restrict__ bq, const float* __restrict__ bk, const float* __restrict__ bv,
    unsigned short* __restrict__ q_ws, unsigned short* __restrict__ k_ws,
    unsigned short* __restrict__ vt_ws) {
    __shared__ __align__(16) unsigned short As[128 * 32];
    __shared__ __align__(16) unsigned short Bs[128 * 32];
    const int z = blockIdx.z;
    const unsigned short* W = (z == 0) ? wq : ((z == 1) ? wk : wv);
    const float* bias = (z == 0) ? bq : ((z == 1) ? bk : bv);
    const float scale = (z == 0) ? 0.125f : 1.0f;
    const int m0 = blockIdx.y * 128;
    const int n0 = blockIdx.x * 128;

    f32x4 acc[4][4];
    gemm_core_128(xbf, W, m0, n0, 1024, As, Bs, acc);

    const int tid = threadIdx.x;
    const int lane = tid & 63;
    const int wid = tid >> 6;
    const int wr = wid >> 1, wc = wid & 1;
    const int l16 = lane & 15, lg = lane >> 4;

#pragma unroll
    for (int j = 0; j < 4; j++) {
        const int c = n0 + 64 * wc + 16 * j + l16;   // output feature
        const float bc = bias[c];
        const int h = c >> 6, d = c & 63;
#pragma unroll
        for (int i = 0; i < 4; i++) {
            const int mb = m0 + 64 * wr + 16 * i + 4 * lg;   // + r
            if (z < 2) {
                unsigned short* dst = (z == 0) ? q_ws : k_ws;
#pragma unroll
                for (int r = 0; r < 4; r++) {
                    int m = mb + r;
                    int b = m >> 11, n = m & 2047;
                    float v = (acc[i][j][r] + bc) * scale;
                    dst[(((b * 16 + h) * 2048 + n) << 6) + d] = f2bf(v);
                }
            } else {
                int b = mb >> 11, n = mb & 2047;   // 4 consecutive n, same b
                ushort4v pk;
                pk.x = f2bf(acc[i][j][0] + bc);
                pk.y = f2bf(acc[i][j][1] + bc);
                pk.z = f2bf(acc[i][j][2] + bc);
                pk.w = f2bf(acc[i][j][3] + bc);
                *reinterpret_cast<ushort4v*>(&vt_ws[((b * 16 + h) * 64 + d) * 2048 + n]) = pk;
            }
        }
    }
}

// ---- Flash attention v2: swapped QK^T, paired q-tiles, causal ----
// 1 wave handles q-tiles t=p (A) and t=127-p (B), 16 rows each; KV tiles of 32.
// Swapped mfma(K,Q): lane owns q-row = l16; scores k = kv0 + {0,16} + 4*lg + r.
__global__ __launch_bounds__(256) void attn_kernel(
    const unsigned short* __restrict__ q_ws, const unsigned short* __restrict__ k_ws,
    const unsigned short* __restrict__ vt_ws, unsigned short* __restrict__ attn_out) {
    __shared__ __align__(16) unsigned short P_lds[4][2][16][40];   // wave, slot(A/B), q-row, k(+pad)
    const int tid = threadIdx.x;
    const int wid = tid >> 6, lane = tid & 63;
    const int l16 = lane & 15, lg = lane >> 4;
    const int gwid = blockIdx.x * 4 + wid;   // 0..2047
    const int bh = gwid >> 6;                // 0..31
    const int p = gwid & 63;
    const int qA0 = p << 4;                  // 0..1008
    const int qB0 = 2032 - (p << 4);         // 2032..1024
    const unsigned short* qb = q_ws + bh * (2048 * 64);
    const unsigned short* kb = k_ws + bh * (2048 * 64);
    const unsigned short* vb = vt_ws + bh * (64 * 2048);

    // Q fragments (hoisted; Q pre-scaled 1/8). Operand layout [q=l16][d=8lg+j].
    bf16x8 aqA0 = *reinterpret_cast<const bf16x8*>(&qb[(qA0 + l16) * 64 + 8 * lg]);
    bf16x8 aqA1 = *reinterpret_cast<const bf16x8*>(&qb[(qA0 + l16) * 64 + 32 + 8 * lg]);
    bf16x8 aqB0 = *reinterpret_cast<const bf16x8*>(&qb[(qB0 + l16) * 64 + 8 * lg]);
    bf16x8 aqB1 = *reinterpret_cast<const bf16x8*>(&qb[(qB0 + l16) * 64 + 32 + 8 * lg]);

    f32x4 oA[4], oB[4];
#pragma unroll
    for (int j = 0; j < 4; j++) { oA[j] = f32x4{0.f, 0.f, 0.f, 0.f}; oB[j] = f32x4{0.f, 0.f, 0.f, 0.f}; }
    float mA = -1e30f, lA = 0.f, mB = -1e30f, lB = 0.f;

    // K prefetch for kv0 = 0 (fragment [k=l16][d=8lg+j], two 16-row k-subtiles)
    bf16x8 k00 = *reinterpret_cast<const bf16x8*>(&kb[l16 * 64 + 8 * lg]);
    bf16x8 k01 = *reinterpret_cast<const bf16x8*>(&kb[l16 * 64 + 32 + 8 * lg]);
    bf16x8 k10 = *reinterpret_cast<const bf16x8*>(&kb[(16 + l16) * 64 + 8 * lg]);
    bf16x8 k11 = *reinterpret_cast<const bf16x8*>(&kb[(16 + l16) * 64 + 32 + 8 * lg]);

    const int kvEnd = qB0 + 16;
    for (int kv0 = 0; kv0 < kvEnd; kv0 += 32) {
        // V-tile loads issued early (used after softmax); shared by A and B.
        bf16x8 v0 = *reinterpret_cast<const bf16x8*>(&vb[l16 * 2048 + kv0 + 8 * lg]);
        bf16x8 v1 = *reinterpret_cast<const bf16x8*>(&vb[(16 + l16) * 2048 + kv0 + 8 * lg]);
        bf16x8 v2 = *reinterpret_cast<const bf16x8*>(&vb[(32 + l16) * 2048 + kv0 + 8 * lg]);
        bf16x8 v3 = *reinterpret_cast<const bf16x8*>(&vb[(48 + l16) * 2048 + kv0 + 8 * lg]);

        const f32x4 z = f32x4{0.f, 0.f, 0.f, 0.f};
        // swapped QK^T: D[k][q], lane: q=l16, k=4lg+r (+16 for second subtile)
        f32x4 sB0 = __builtin_amdgcn_mfma_f32_16x16x32_bf16(k00, aqB0, z, 0, 0, 0);
        sB0 = __builtin_amdgcn_mfma_f32_16x16x32_bf16(k01, aqB1, sB0, 0, 0, 0);
        f32x4 sB1 = __builtin_amdgcn_mfma_f32_16x16x32_bf16(k10, aqB0, z, 0, 0, 0);
        sB1 = __builtin_amdgcn_mfma_f32_16x16x32_bf16(k11, aqB1, sB1, 0, 0, 0);
        const bool actA = kv0 < qA0 + 16;
        f32x4 sA0 = z, sA1 = z;
        if (actA) {
            sA0 = __builtin_amdgcn_mfma_f32_16x16x32_bf16(k00, aqA0, z, 0, 0, 0);
            sA0 = __builtin_amdgcn_mfma_f32_16x16x32_bf16(k01, aqA1, sA0, 0, 0, 0);
            sA1 = __builtin_amdgcn_mfma_f32_16x16x32_bf16(k10, aqA0, z, 0, 0, 0);
            sA1 = __builtin_amdgcn_mfma_f32_16x16x32_bf16(k11, aqA1, sA1, 0, 0, 0);
        }
        // prefetch next K tile (K regs no longer needed this iter)
        if (kv0 + 32 < kvEnd) {
            const unsigned short* kr0 = &kb[(kv0 + 32 + l16) * 64 + 8 * lg];
            const unsigned short* kr1 = &kb[(kv0 + 48 + l16) * 64 + 8 * lg];
            k00 = *reinterpret_cast<const bf16x8*>(kr0);
            k01 = *reinterpret_cast<const bf16x8*>(kr0 + 32);
            k10 = *reinterpret_cast<const bf16x8*>(kr1);
            k11 = *reinterpret_cast<const bf16x8*>(kr1 + 32);
        }

        // softmax + PV for one tile; slot selects A/B LDS region
        auto process = [&](f32x4 s0, f32x4 s1, int qX0, float& mX, float& lX,
                           f32x4* o, int slot) {
            const int kbase = kv0 + 4 * lg;
            const int qrow = qX0 + l16;
#pragma unroll
            for (int r = 0; r < 4; r++) {
                if (kbase + r > qrow) s0[r] = -1e30f;
                if (kbase + 16 + r > qrow) s1[r] = -1e30f;
            }
            float mx = fmaxf(fmaxf(fmaxf(s0[0], s0[1]), fmaxf(s0[2], s0[3])),
                             fmaxf(fmaxf(s1[0], s1[1]), fmaxf(s1[2], s1[3])));
            mx = fmaxf(mx, __shfl_xor(mx, 16));
            mx = fmaxf(mx, __shfl_xor(mx, 32));
            const float mnew = fmaxf(mX, mx);
            const float sf = __expf(mX - mnew);
            mX = mnew;
            float p0[4], p1[4];
#pragma unroll
            for (int r = 0; r < 4; r++) {
                p0[r] = __expf(s0[r] - mnew);
                p1[r] = __expf(s1[r] - mnew);
            }
            float sum = ((p0[0] + p0[1]) + (p0[2] + p0[3])) +
                        ((p1[0] + p1[1]) + (p1[2] + p1[3]));
            sum += __shfl_xor(sum, 16);
            sum += __shfl_xor(sum, 32);
            lX = lX * sf + sum;
            // P -> LDS (row q=l16, cols k): k=4lg+r and 16+4lg+r, packed bf16
            unsigned int a0 = (unsigned)f2bf(p0[0]) | ((unsigned)f2bf(p0[1]) << 16);
            unsigned int a1 = (unsigned)f2bf(p0[2]) | ((unsigned)f2bf(p0[3]) << 16);
            unsigned int b0 = (unsigned)f2bf(p1[0]) | ((unsigned)f2bf(p1[1]) << 16);
            unsigned int b1 = (unsigned)f2bf(p1[2]) | ((unsigned)f2bf(p1[3]) << 16);
            *reinterpret_cast<uint2*>(&P_lds[wid][slot][l16][4 * lg]) = make_uint2(a0, a1);
            *reinterpret_cast<uint2*>(&P_lds[wid][slot][l16][16 + 4 * lg]) = make_uint2(b0, b1);
            // o-rescale: o rows are q=4lg+r -> transpose sf across lanes
            float sfT[4];
#pragma unroll
            for (int r = 0; r < 4; r++) sfT[r] = __shfl(sf, 4 * lg + r);
#pragma unroll
            for (int j = 0; j < 4; j++) {
                o[j][0] *= sfT[0]; o[j][1] *= sfT[1];
                o[j][2] *= sfT[2]; o[j][3] *= sfT[3];
            }
            // P A-fragment [q=l16][k=8lg+j] and PV
            bf16x8 pf = *reinterpret_cast<const bf16x8*>(&P_lds[wid][slot][l16][8 * lg]);
            o[0] = __builtin_amdgcn_mfma_f32_16x16x32_bf16(pf, v0, o[0], 0, 0, 0);
            o[1] = __builtin_amdgcn_mfma_f32_16x16x32_bf16(pf, v1, o[1], 0, 0, 0);
            o[2] = __builtin_amdgcn_mfma_f32_16x16x32_bf16(pf, v2, o[2], 0, 0, 0);
            o[3] = __builtin_amdgcn_mfma_f32_16x16x32_bf16(pf, v3, o[3], 0, 0, 0);
        };
        process(sB0, sB1, qB0, mB, lB, oB, 1);
        if (actA) process(sA0, sA1, qA0, mA, lA, oA, 0);
    }

    // epilogue: o rows q=4lg+r need l at that q -> transpose l via shfl
    const int b = bh >> 4, h = bh & 15;
    auto epi = [&](int qX0, float lX, f32x4* o) {
        float inv[4];
#pragma unroll
        for (int r = 0; r < 4; r++) inv[r] = 1.0f / __shfl(lX, 4 * lg + r);
#pragma unroll
        for (int j = 0; j < 4; j++)
#pragma unroll
            for (int r = 0; r < 4; r++) {
                int n = qX0 + 4 * lg + r;
                attn_out[(size_t)(b * 2048 + n) * 1024 + h * 64 + 16 * j + l16] =
                    f2bf(o[j][r] * inv[r]);
            }
    };
    epi(qA0, lA, oA);
    epi(qB0, lB, oB);
}

// ---- output projection: out = attn_out @ Wo^T (f32 out, no bias) ----
__global__ __launch_bounds__(256) void gemm_out_kernel(
    const unsigned short* __restrict__ abf, const unsigned short* __restrict__ wo,
    float* __restrict__ out) {
    __shared__ __align__(16) unsigned short As[128 * 32];
    __shared__ __align__(16) unsigned short Bs[128 * 32];
    const int m0 = blockIdx.y * 128;
    const int n0 = blockIdx.x * 128;
    f32x4 acc[4][4];
    gemm_core_128(abf, wo, m0, n0, 1024, As, Bs, acc);

    const int tid = threadIdx.x;
    const int lane = tid & 63;
    const int wid = tid >> 6;
    const int wr = wid >> 1, wc = wid & 1;
    const int l16 = lane & 15, lg = lane >> 4;
#pragma unroll
    for (int j = 0; j < 4; j++) {
        const int c = n0 + 64 * wc + 16 * j + l16;
#pragma unroll
        for (int i = 0; i < 4; i++) {
#pragma unroll
            for (int r = 0; r < 4; r++) {
                int m = m0 + 64 * wr + 16 * i + 4 * lg + r;
                out[(size_t)m * 1024 + c] = acc[i][j][r];
            }
        }
    }
}

extern "C" void kernel_launch(void* const* d_in, const int* in_sizes, int n_in,
                              void* d_out, int out_size, void* d_ws, size_t ws_size,
                              hipStream_t stream) {
    const float* x  = (const float*)d_in[0];
    const float* Wq = (const float*)d_in[1];
    const float* bq = (const float*)d_in[2];
    const float* Wk = (const float*)d_in[3];
    const float* bk = (const float*)d_in[4];
    const float* Wv = (const float*)d_in[5];
    const float* bv = (const float*)d_in[6];
    const float* Wo = (const float*)d_in[7];
    float* out = (float*)d_out;

    char* ws = (char*)d_ws;
    unsigned short* xbf  = (unsigned short*)(ws);
    unsigned short* wqbf = (unsigned short*)(ws + (8u  << 20));
    unsigned short* wkbf = (unsigned short*)(ws + (10u << 20));
    unsigned short* wvbf = (unsigned short*)(ws + (12u << 20));
    unsigned short* wobf = (unsigned short*)(ws + (14u << 20));
    unsigned short* qws  = (unsigned short*)(ws + (16u << 20));
    unsigned short* kws  = (unsigned short*)(ws + (24u << 20));
    unsigned short* vtws = (unsigned short*)(ws + (32u << 20));
    unsigned short* aows = (unsigned short*)(ws + (40u << 20));

    cast_bf16_kernel<<<4096, 256, 0, stream>>>(x, xbf, 4096 * 1024 / 4);
    cast_w4_kernel<<<dim3(1024, 4), 256, 0, stream>>>(
        Wq, Wk, Wv, Wo, wqbf, wkbf, wvbf, wobf);

    gemm_qkv_kernel<<<dim3(8, 32, 3), 256, 0, stream>>>(
        xbf, wqbf, wkbf, wvbf, bq, bk, bv, qws, kws, vtws);

    // attention: 2048 waves, each owns q-tiles (p, 127-p) for one (b,h)
    attn_kernel<<<512, 256, 0, stream>>>(qws, kws, vtws, aows);

    gemm_out_kernel<<<dim3(8, 32, 1), 256, 0, stream>>>(aows, wobf, out);
}

// Round 6
// 274.104 us; speedup vs baseline: 1.4599x; 1.0254x over previous
//
#include <hip/hip_runtime.h>
#include <hip/hip_bf16.h>

// Fused causal MHA for MI355X (gfx950).
// Round-5 changes:
//  * Attention VALU diet: log2-domain softmax (exp2 native), defer-max (T13),
//    diagonal-only masking, v_cvt_pk_bf16_f32 packing.
//  * GEMMs: 128x64 tiles -> 6 blocks/CU (qkv) for wave-level overlap.
// Workspace layout (48 MB):
//   [0,8M) x_bf16 | [8,16M) Wq/Wk/Wv/Wo bf16 (2M each)
//   [16,24M) Q (b,h,n,d) bf16 pre-scaled 0.125*log2(e) | [24,32M) K (b,h,n,d)
//   [32,40M) V^T (b,h,d,n) | [40,48M) attn_out (b,n,h*dv) bf16

using bf16x8   = __attribute__((ext_vector_type(8))) __bf16;
using f32x4    = __attribute__((ext_vector_type(4))) float;
using ushort4v = __attribute__((ext_vector_type(4))) unsigned short;

__device__ __forceinline__ unsigned short f2bf(float f) {
    unsigned int u = __float_as_uint(f);
    u += 0x7FFFu + ((u >> 16) & 1u);   // round-to-nearest-even
    return (unsigned short)(u >> 16);
}

// packed f32 pair -> bf16 pair (lo in [15:0], hi in [31:16]), RNE
__device__ __forceinline__ unsigned cvtpk(float lo, float hi) {
    unsigned r;
    asm("v_cvt_pk_bf16_f32 %0, %1, %2" : "=v"(r) : "v"(lo), "v"(hi));
    return r;
}

__device__ __forceinline__ void gll16(const void* g, void* l) {
    __builtin_amdgcn_global_load_lds(
        (const __attribute__((address_space(1))) void*)g,
        (__attribute__((address_space(3))) void*)l, 16, 0, 0);
}

__global__ __launch_bounds__(256) void cast_bf16_kernel(
    const float* __restrict__ in, unsigned short* __restrict__ out, int n4) {
    int i = blockIdx.x * 256 + threadIdx.x;
    if (i >= n4) return;
    float4 f = reinterpret_cast<const float4*>(in)[i];
    ushort4v o;
    o.x = f2bf(f.x); o.y = f2bf(f.y); o.z = f2bf(f.z); o.w = f2bf(f.w);
    reinterpret_cast<ushort4v*>(out)[i] = o;
}

__global__ __launch_bounds__(256) void cast_w4_kernel(
    const float* __restrict__ w0, const float* __restrict__ w1,
    const float* __restrict__ w2, const float* __restrict__ w3,
    unsigned short* __restrict__ o0, unsigned short* __restrict__ o1,
    unsigned short* __restrict__ o2, unsigned short* __restrict__ o3) {
    const int z = blockIdx.y;
    const float* in = (z == 0) ? w0 : (z == 1) ? w1 : (z == 2) ? w2 : w3;
    unsigned short* out = (z == 0) ? o0 : (z == 1) ? o1 : (z == 2) ? o2 : o3;
    int i = blockIdx.x * 256 + threadIdx.x;
    float4 f = reinterpret_cast<const float4*>(in)[i];
    ushort4v o;
    o.x = f2bf(f.x); o.y = f2bf(f.y); o.z = f2bf(f.z); o.w = f2bf(f.w);
    reinterpret_cast<ushort4v*>(out)[i] = o;
}

// ---- 128x64 GEMM core, global_load_lds staging ----
// C = A(MxK=128 rows) * B(NxK=64 rows)^T. LDS linear As[128][32], Bs[64][32].
// 4 waves 2x2 (wr: 64 rows, wc: 32 cols); per wave 64x32 = 4x2 MFMA frags.
__device__ __forceinline__ void gemm_core_128x64(
    const unsigned short* __restrict__ A, const unsigned short* __restrict__ B,
    int m0, int n0, int K,
    unsigned short* As, unsigned short* Bs, f32x4 acc[4][2]) {
    const int tid = threadIdx.x;
    const int lane = tid & 63;
    const int wid = tid >> 6;
    const int wr = wid >> 1, wc = wid & 1;
    const int l16 = lane & 15, lg = lane >> 4;

#pragma unroll
    for (int i = 0; i < 4; i++)
#pragma unroll
        for (int j = 0; j < 2; j++) acc[i][j] = f32x4{0.f, 0.f, 0.f, 0.f};

    const int srow = lane >> 2;         // 0..15
    const int scol = (lane & 3) * 8;    // 0,8,16,24
    const unsigned short* Ab0 = &A[(size_t)(m0 + wid * 16 + srow) * K + scol];
    const unsigned short* Ab1 = &A[(size_t)(m0 + 64 + wid * 16 + srow) * K + scol];
    const unsigned short* Bb0 = &B[(size_t)(n0 + wid * 16 + srow) * K + scol];
    unsigned short* AsW0 = As + (wid * 16) * 32;   // wave-uniform LDS bases
    unsigned short* AsW1 = As + (64 + wid * 16) * 32;
    unsigned short* BsW0 = Bs + (wid * 16) * 32;

    for (int k0 = 0; k0 < K; k0 += 32) {
        __syncthreads();                   // prev-iter LDS reads done
        gll16(Ab0 + k0, AsW0);
        gll16(Ab1 + k0, AsW1);
        gll16(Bb0 + k0, BsW0);
        __syncthreads();                   // vmcnt drained before barrier
        bf16x8 af[4], bfr[2];
#pragma unroll
        for (int i = 0; i < 4; i++)
            af[i] = *reinterpret_cast<const bf16x8*>(&As[(64 * wr + 16 * i + l16) * 32 + 8 * lg]);
#pragma unroll
        for (int j = 0; j < 2; j++)
            bfr[j] = *reinterpret_cast<const bf16x8*>(&Bs[(32 * wc + 16 * j + l16) * 32 + 8 * lg]);
#pragma unroll
        for (int i = 0; i < 4; i++)
#pragma unroll
            for (int j = 0; j < 2; j++)
                acc[i][j] = __builtin_amdgcn_mfma_f32_16x16x32_bf16(af[i], bfr[j], acc[i][j], 0, 0, 0);
    }
}

// ---- QKV projection: z=0 -> Q (scaled 0.125*log2e), z=1 -> K, z=2 -> V^T ----
__global__ __launch_bounds__(256) void gemm_qkv_kernel(
    const unsigned short* __restrict__ xbf,
    const unsigned short* __restrict__ wq, const unsigned short* __restrict__ wk,
    const unsigned short* __restrict__ wv,
    const float* __restrict__ bq, const float* __restrict__ bk, const float* __restrict__ bv,
    unsigned short* __restrict__ q_ws, unsigned short* __restrict__ k_ws,
    unsigned short* __restrict__ vt_ws) {
    __shared__ __align__(16) unsigned short As[128 * 32];
    __shared__ __align__(16) unsigned short Bs[64 * 32];
    const int z = blockIdx.z;
    const unsigned short* W = (z == 0) ? wq : ((z == 1) ? wk : wv);
    const float* bias = (z == 0) ? bq : ((z == 1) ? bk : bv);
    // log2-domain softmax: fold log2(e) into Q scale
    const float scale = (z == 0) ? 0.125f * 1.44269504f : 1.0f;
    const int m0 = blockIdx.y * 128;
    const int n0 = blockIdx.x * 64;

    f32x4 acc[4][2];
    gemm_core_128x64(xbf, W, m0, n0, 1024, As, Bs, acc);

    const int tid = threadIdx.x;
    const int lane = tid & 63;
    const int wid = tid >> 6;
    const int wr = wid >> 1, wc = wid & 1;
    const int l16 = lane & 15, lg = lane >> 4;

#pragma unroll
    for (int j = 0; j < 2; j++) {
        const int c = n0 + 32 * wc + 16 * j + l16;   // output feature
        const float bc = bias[c];
        const int h = c >> 6, d = c & 63;
#pragma unroll
        for (int i = 0; i < 4; i++) {
            const int mb = m0 + 64 * wr + 16 * i + 4 * lg;   // + r
            if (z < 2) {
                unsigned short* dst = (z == 0) ? q_ws : k_ws;
#pragma unroll
                for (int r = 0; r < 4; r++) {
                    int m = mb + r;
                    int b = m >> 11, n = m & 2047;
                    float v = (acc[i][j][r] + bc) * scale;
                    dst[(((b * 16 + h) * 2048 + n) << 6) + d] = f2bf(v);
                }
            } else {
                int b = mb >> 11, n = mb & 2047;   // 4 consecutive n, same b
                ushort4v pk;
                pk.x = f2bf(acc[i][j][0] + bc);
                pk.y = f2bf(acc[i][j][1] + bc);
                pk.z = f2bf(acc[i][j][2] + bc);
                pk.w = f2bf(acc[i][j][3] + bc);
                *reinterpret_cast<ushort4v*>(&vt_ws[((b * 16 + h) * 64 + d) * 2048 + n]) = pk;
            }
        }
    }
}

// ---- Flash attention v3: swapped QK^T, paired q-tiles, log2 softmax,
//      defer-max, diagonal-only masking ----
__global__ __launch_bounds__(256) void attn_kernel(
    const unsigned short* __restrict__ q_ws, const unsigned short* __restrict__ k_ws,
    const unsigned short* __restrict__ vt_ws, unsigned short* __restrict__ attn_out) {
    __shared__ __align__(16) unsigned short P_lds[4][2][16][40];   // wave, slot, q-row, k(+pad)
    const int tid = threadIdx.x;
    const int wid = tid >> 6, lane = tid & 63;
    const int l16 = lane & 15, lg = lane >> 4;
    const int gwid = blockIdx.x * 4 + wid;   // 0..2047
    const int bh = gwid >> 6;                // 0..31
    const int p = gwid & 63;
    const int qA0 = p << 4;                  // 0..1008
    const int qB0 = 2032 - (p << 4);         // 2032..1024
    const unsigned short* qb = q_ws + bh * (2048 * 64);
    const unsigned short* kb = k_ws + bh * (2048 * 64);
    const unsigned short* vb = vt_ws + bh * (64 * 2048);

    // Q fragments (hoisted; pre-scaled). Operand layout [q=l16][d=8lg+j].
    bf16x8 aqA0 = *reinterpret_cast<const bf16x8*>(&qb[(qA0 + l16) * 64 + 8 * lg]);
    bf16x8 aqA1 = *reinterpret_cast<const bf16x8*>(&qb[(qA0 + l16) * 64 + 32 + 8 * lg]);
    bf16x8 aqB0 = *reinterpret_cast<const bf16x8*>(&qb[(qB0 + l16) * 64 + 8 * lg]);
    bf16x8 aqB1 = *reinterpret_cast<const bf16x8*>(&qb[(qB0 + l16) * 64 + 32 + 8 * lg]);

    f32x4 oA[4], oB[4];
#pragma unroll
    for (int j = 0; j < 4; j++) { oA[j] = f32x4{0.f, 0.f, 0.f, 0.f}; oB[j] = f32x4{0.f, 0.f, 0.f, 0.f}; }
    float mA = -1e30f, lA = 0.f, mB = -1e30f, lB = 0.f;

    // K prefetch for kv0 = 0
    bf16x8 k00 = *reinterpret_cast<const bf16x8*>(&kb[l16 * 64 + 8 * lg]);
    bf16x8 k01 = *reinterpret_cast<const bf16x8*>(&kb[l16 * 64 + 32 + 8 * lg]);
    bf16x8 k10 = *reinterpret_cast<const bf16x8*>(&kb[(16 + l16) * 64 + 8 * lg]);
    bf16x8 k11 = *reinterpret_cast<const bf16x8*>(&kb[(16 + l16) * 64 + 32 + 8 * lg]);

    const int kvEnd = qB0 + 16;
    for (int kv0 = 0; kv0 < kvEnd; kv0 += 32) {
        // V-tile loads (used after softmax); shared by A and B.
        bf16x8 v0 = *reinterpret_cast<const bf16x8*>(&vb[l16 * 2048 + kv0 + 8 * lg]);
        bf16x8 v1 = *reinterpret_cast<const bf16x8*>(&vb[(16 + l16) * 2048 + kv0 + 8 * lg]);
        bf16x8 v2 = *reinterpret_cast<const bf16x8*>(&vb[(32 + l16) * 2048 + kv0 + 8 * lg]);
        bf16x8 v3 = *reinterpret_cast<const bf16x8*>(&vb[(48 + l16) * 2048 + kv0 + 8 * lg]);

        const f32x4 z = f32x4{0.f, 0.f, 0.f, 0.f};
        // swapped QK^T: lane: q=l16, k=kv0 + {0,16} + 4lg + r
        f32x4 sB0 = __builtin_amdgcn_mfma_f32_16x16x32_bf16(k00, aqB0, z, 0, 0, 0);
        sB0 = __builtin_amdgcn_mfma_f32_16x16x32_bf16(k01, aqB1, sB0, 0, 0, 0);
        f32x4 sB1 = __builtin_amdgcn_mfma_f32_16x16x32_bf16(k10, aqB0, z, 0, 0, 0);
        sB1 = __builtin_amdgcn_mfma_f32_16x16x32_bf16(k11, aqB1, sB1, 0, 0, 0);
        const bool actA = kv0 < qA0 + 16;
        f32x4 sA0 = z, sA1 = z;
        if (actA) {
            sA0 = __builtin_amdgcn_mfma_f32_16x16x32_bf16(k00, aqA0, z, 0, 0, 0);
            sA0 = __builtin_amdgcn_mfma_f32_16x16x32_bf16(k01, aqA1, sA0, 0, 0, 0);
            sA1 = __builtin_amdgcn_mfma_f32_16x16x32_bf16(k10, aqA0, z, 0, 0, 0);
            sA1 = __builtin_amdgcn_mfma_f32_16x16x32_bf16(k11, aqA1, sA1, 0, 0, 0);
        }
        // prefetch next K tile
        if (kv0 + 32 < kvEnd) {
            const unsigned short* kr0 = &kb[(kv0 + 32 + l16) * 64 + 8 * lg];
            const unsigned short* kr1 = &kb[(kv0 + 48 + l16) * 64 + 8 * lg];
            k00 = *reinterpret_cast<const bf16x8*>(kr0);
            k01 = *reinterpret_cast<const bf16x8*>(kr0 + 32);
            k10 = *reinterpret_cast<const bf16x8*>(kr1);
            k11 = *reinterpret_cast<const bf16x8*>(kr1 + 32);
        }

        // softmax (log2 domain) + PV for one q-tile
        auto process = [&](f32x4 s0, f32x4 s1, int qX0, float& mX, float& lX,
                           f32x4* o, int slot, bool diag) {
            if (diag) {   // wave-uniform branch: only last tile per q-tile
                const int kbase = kv0 + 4 * lg;
                const int qrow = qX0 + l16;
#pragma unroll
                for (int r = 0; r < 4; r++) {
                    if (kbase + r > qrow) s0[r] = -1e30f;
                    if (kbase + 16 + r > qrow) s1[r] = -1e30f;
                }
            }
            float mx = fmaxf(fmaxf(fmaxf(s0[0], s0[1]), fmaxf(s0[2], s0[3])),
                             fmaxf(fmaxf(s1[0], s1[1]), fmaxf(s1[2], s1[3])));
            mx = fmaxf(mx, __shfl_xor(mx, 16));
            mx = fmaxf(mx, __shfl_xor(mx, 32));
            // defer-max (T13): only rescale when the running max grew by >8
            if (!__all(mx <= mX + 8.0f)) {
                const float mnew = fmaxf(mX, mx);
                const float sf = __builtin_amdgcn_exp2f(mX - mnew);
                mX = mnew;
                lX *= sf;
                float sfT[4];
#pragma unroll
                for (int r = 0; r < 4; r++) sfT[r] = __shfl(sf, 4 * lg + r);
#pragma unroll
                for (int j = 0; j < 4; j++) {
                    o[j][0] *= sfT[0]; o[j][1] *= sfT[1];
                    o[j][2] *= sfT[2]; o[j][3] *= sfT[3];
                }
            }
            float p0[4], p1[4];
#pragma unroll
            for (int r = 0; r < 4; r++) {
                p0[r] = __builtin_amdgcn_exp2f(s0[r] - mX);
                p1[r] = __builtin_amdgcn_exp2f(s1[r] - mX);
            }
            float sum = ((p0[0] + p0[1]) + (p0[2] + p0[3])) +
                        ((p1[0] + p1[1]) + (p1[2] + p1[3]));
            sum += __shfl_xor(sum, 16);
            sum += __shfl_xor(sum, 32);
            lX += sum;
            // P -> LDS (row q=l16): cols 4lg..4lg+3 and 16+4lg..+3, packed bf16
            uint2 w0 = make_uint2(cvtpk(p0[0], p0[1]), cvtpk(p0[2], p0[3]));
            uint2 w1 = make_uint2(cvtpk(p1[0], p1[1]), cvtpk(p1[2], p1[3]));
            *reinterpret_cast<uint2*>(&P_lds[wid][slot][l16][4 * lg]) = w0;
            *reinterpret_cast<uint2*>(&P_lds[wid][slot][l16][16 + 4 * lg]) = w1;
            bf16x8 pf = *reinterpret_cast<const bf16x8*>(&P_lds[wid][slot][l16][8 * lg]);
            o[0] = __builtin_amdgcn_mfma_f32_16x16x32_bf16(pf, v0, o[0], 0, 0, 0);
            o[1] = __builtin_amdgcn_mfma_f32_16x16x32_bf16(pf, v1, o[1], 0, 0, 0);
            o[2] = __builtin_amdgcn_mfma_f32_16x16x32_bf16(pf, v2, o[2], 0, 0, 0);
            o[3] = __builtin_amdgcn_mfma_f32_16x16x32_bf16(pf, v3, o[3], 0, 0, 0);
        };
        const bool diagB = (kv0 + 32 >= kvEnd);
        process(sB0, sB1, qB0, mB, lB, oB, 1, diagB);
        if (actA) {
            const bool diagA = (kv0 + 32 >= qA0 + 16);
            process(sA0, sA1, qA0, mA, lA, oA, 0, diagA);
        }
    }

    // epilogue: o rows q=4lg+r need l at that q -> transpose l via shfl
    const int b = bh >> 4, h = bh & 15;
    auto epi = [&](int qX0, float lX, f32x4* o) {
        float inv[4];
#pragma unroll
        for (int r = 0; r < 4; r++) inv[r] = 1.0f / __shfl(lX, 4 * lg + r);
#pragma unroll
        for (int j = 0; j < 4; j++)
#pragma unroll
            for (int r = 0; r < 4; r++) {
                int n = qX0 + 4 * lg + r;
                attn_out[(size_t)(b * 2048 + n) * 1024 + h * 64 + 16 * j + l16] =
                    f2bf(o[j][r] * inv[r]);
            }
    };
    epi(qA0, lA, oA);
    epi(qB0, lB, oB);
}

// ---- output projection: out = attn_out @ Wo^T (f32 out, no bias) ----
__global__ __launch_bounds__(256) void gemm_out_kernel(
    const unsigned short* __restrict__ abf, const unsigned short* __restrict__ wo,
    float* __restrict__ out) {
    __shared__ __align__(16) unsigned short As[128 * 32];
    __shared__ __align__(16) unsigned short Bs[64 * 32];
    const int m0 = blockIdx.y * 128;
    const int n0 = blockIdx.x * 64;
    f32x4 acc[4][2];
    gemm_core_128x64(abf, wo, m0, n0, 1024, As, Bs, acc);

    const int tid = threadIdx.x;
    const int lane = tid & 63;
    const int wid = tid >> 6;
    const int wr = wid >> 1, wc = wid & 1;
    const int l16 = lane & 15, lg = lane >> 4;
#pragma unroll
    for (int j = 0; j < 2; j++) {
        const int c = n0 + 32 * wc + 16 * j + l16;
#pragma unroll
        for (int i = 0; i < 4; i++) {
#pragma unroll
            for (int r = 0; r < 4; r++) {
                int m = m0 + 64 * wr + 16 * i + 4 * lg + r;
                out[(size_t)m * 1024 + c] = acc[i][j][r];
            }
        }
    }
}

extern "C" void kernel_launch(void* const* d_in, const int* in_sizes, int n_in,
                              void* d_out, int out_size, void* d_ws, size_t ws_size,
                              hipStream_t stream) {
    const float* x  = (const float*)d_in[0];
    const float* Wq = (const float*)d_in[1];
    const float* bq = (const float*)d_in[2];
    const float* Wk = (const float*)d_in[3];
    const float* bk = (const float*)d_in[4];
    const float* Wv = (const float*)d_in[5];
    const float* bv = (const float*)d_in[6];
    const float* Wo = (const float*)d_in[7];
    float* out = (float*)d_out;

    char* ws = (char*)d_ws;
    unsigned short* xbf  = (unsigned short*)(ws);
    unsigned short* wqbf = (unsigned short*)(ws + (8u  << 20));
    unsigned short* wkbf = (unsigned short*)(ws + (10u << 20));
    unsigned short* wvbf = (unsigned short*)(ws + (12u << 20));
    unsigned short* wobf = (unsigned short*)(ws + (14u << 20));
    unsigned short* qws  = (unsigned short*)(ws + (16u << 20));
    unsigned short* kws  = (unsigned short*)(ws + (24u << 20));
    unsigned short* vtws = (unsigned short*)(ws + (32u << 20));
    unsigned short* aows = (unsigned short*)(ws + (40u << 20));

    cast_bf16_kernel<<<4096, 256, 0, stream>>>(x, xbf, 4096 * 1024 / 4);
    cast_w4_kernel<<<dim3(1024, 4), 256, 0, stream>>>(
        Wq, Wk, Wv, Wo, wqbf, wkbf, wvbf, wobf);

    // QKV: 128x64 tiles -> (16, 32, 3) = 1536 blocks (~6/CU)
    gemm_qkv_kernel<<<dim3(16, 32, 3), 256, 0, stream>>>(
        xbf, wqbf, wkbf, wvbf, bq, bk, bv, qws, kws, vtws);

    // attention: 2048 waves, each owns q-tiles (p, 127-p) for one (b,h)
    attn_kernel<<<512, 256, 0, stream>>>(qws, kws, vtws, aows);

    // out projection: 128x64 tiles -> (16, 32) = 512 blocks
    gemm_out_kernel<<<dim3(16, 32), 256, 0, stream>>>(aows, wobf, out);
}